// Round 1
// baseline (149.405 us; speedup 1.0000x reference)
//
#include <hip/hip_runtime.h>

typedef __attribute__((ext_vector_type(8))) short short8;
typedef __attribute__((ext_vector_type(4))) float f32x4;
typedef unsigned short ushort_t;

#define N_OSC   256
#define NUM_CN  32
#define BATCH   64
#define T_STEPS 40
#define DT      0.125f

#define GK      8192    // GEMM K
#define GN      8192    // GEMM N
#define BN      64      // N per block
#define KSPLIT  8
#define KRANGE  1024    // GK / KSPLIT
#define WKR     256     // KRANGE / 4 waves
#define PH_ELEMS 655360 // 40*64*256

__device__ __forceinline__ unsigned short f2bf(float f) {
    unsigned u = __float_as_uint(f);
    return (unsigned short)((u + 0x7fffu + ((u >> 16) & 1u)) >> 16);
}

// ---------------- Kernel 1: conv stack -> feat (bf16) ----------------
// grid 256 (4 blocks per batch, 8 out-channels each), block 256 (one pixel each)
__global__ __launch_bounds__(256) void conv_kernel(
    const float* __restrict__ x,  const float* __restrict__ w0,
    const float* __restrict__ b0, const float* __restrict__ w1,
    const float* __restrict__ b1, ushort_t* __restrict__ featB)
{
    __shared__ float xs[3][256];
    __shared__ float h0[16][256];
    int blk = blockIdx.x;
    int b = blk >> 2, og = blk & 3;
    int p = threadIdx.x;
    int y = p >> 4, x0 = p & 15;

    #pragma unroll
    for (int c = 0; c < 3; ++c) xs[c][p] = x[b * 768 + c * 256 + p];
    __syncthreads();

    float acc0[16];
    #pragma unroll
    for (int o = 0; o < 16; ++o) acc0[o] = b0[o];
    #pragma unroll
    for (int c = 0; c < 3; ++c)
        #pragma unroll
        for (int ky = 0; ky < 3; ++ky) {
            int yy = y + ky - 1;
            if (yy < 0 || yy > 15) continue;
            #pragma unroll
            for (int kx = 0; kx < 3; ++kx) {
                int xx = x0 + kx - 1;
                if (xx < 0 || xx > 15) continue;
                float v = xs[c][yy * 16 + xx];
                #pragma unroll
                for (int o = 0; o < 16; ++o)
                    acc0[o] = fmaf(v, w0[o * 27 + c * 9 + ky * 3 + kx], acc0[o]);
            }
        }
    #pragma unroll
    for (int o = 0; o < 16; ++o) h0[o][p] = tanhf(acc0[o]);
    __syncthreads();

    float acc1[8];
    #pragma unroll
    for (int o = 0; o < 8; ++o) acc1[o] = b1[og * 8 + o];
    for (int c = 0; c < 16; ++c)
        #pragma unroll
        for (int ky = 0; ky < 3; ++ky) {
            int yy = y + ky - 1;
            if (yy < 0 || yy > 15) continue;
            #pragma unroll
            for (int kx = 0; kx < 3; ++kx) {
                int xx = x0 + kx - 1;
                if (xx < 0 || xx > 15) continue;
                float v = h0[c][yy * 16 + xx];
                #pragma unroll
                for (int o = 0; o < 8; ++o)
                    acc1[o] = fmaf(v, w1[(og * 8 + o) * 144 + c * 9 + ky * 3 + kx], acc1[o]);
            }
        }
    #pragma unroll
    for (int o = 0; o < 8; ++o)
        featB[b * 8192 + (og * 8 + o) * 256 + p] = f2bf(tanhf(acc1[o]));
}

// ---------------- Kernel 2: split-K MFMA GEMM ----------------
// grid (GN/BN=128, KSPLIT=8), block 256. Each wave owns a 256-long K slice,
// computes the full 64x64 tile; waves reduce in LDS; partials -> d_out K region.
__global__ __launch_bounds__(256, 3) void gemm_kernel(
    const ushort_t* __restrict__ featB,   // [64][8192] bf16
    const float*    __restrict__ lin_w,   // [8192][8192]
    float*          __restrict__ partials)// [KSPLIT][64][8192]
{
    __shared__ float red[64][65];
    int tid = threadIdx.x;
    int lane = tid & 63, wid = tid >> 6;
    int l15 = lane & 15;
    int kg = (lane >> 4) * 8;
    int n0 = blockIdx.x * BN;
    int kslice = blockIdx.y * KRANGE + wid * WKR;

    f32x4 acc[4][4];
    #pragma unroll
    for (int i = 0; i < 4; ++i)
        #pragma unroll
        for (int j = 0; j < 4; ++j) acc[i][j] = (f32x4){0.f, 0.f, 0.f, 0.f};

    const ushort_t* ab = featB + kslice + kg;
    const float* bb = lin_w + (size_t)(kslice + kg) * GN + n0 + l15;

    #pragma unroll 1
    for (int ks = 0; ks < WKR / 32; ++ks) {
        const ushort_t* ap = ab + ks * 32;
        short8 af[4];
        #pragma unroll
        for (int mf = 0; mf < 4; ++mf)
            af[mf] = *(const short8*)(ap + (size_t)(mf * 16 + l15) * GK);

        const float* bp = bb + (size_t)ks * 32 * GN;
        #pragma unroll
        for (int nf = 0; nf < 4; ++nf) {
            short8 bfrag;
            #pragma unroll
            for (int i = 0; i < 8; ++i)
                bfrag[i] = (short)f2bf(bp[(size_t)i * GN + nf * 16]);
            #pragma unroll
            for (int mf = 0; mf < 4; ++mf)
                acc[mf][nf] = __builtin_amdgcn_mfma_f32_16x16x32_bf16(
                    af[mf], bfrag, acc[mf][nf], 0, 0, 0);
        }
    }

    // reduce the 4 waves' tiles in LDS
    for (int w = 0; w < 4; ++w) {
        if (wid == w) {
            #pragma unroll
            for (int mf = 0; mf < 4; ++mf)
                #pragma unroll
                for (int nf = 0; nf < 4; ++nf)
                    #pragma unroll
                    for (int r = 0; r < 4; ++r) {
                        int row = mf * 16 + (lane >> 4) * 4 + r;
                        int col = nf * 16 + l15;
                        if (w == 0) red[row][col] = acc[mf][nf][r];
                        else        red[row][col] += acc[mf][nf][r];
                    }
        }
        __syncthreads();
    }

    float* pout = partials + (size_t)blockIdx.y * (64 * GN) + n0;
    #pragma unroll
    for (int i = 0; i < 16; ++i) {
        int id = i * 256 + tid;
        int m = id >> 6, j = id & 63;
        pout[(size_t)m * GN + j] = red[m][j];
    }
}

// ---------------- Kernel 3: reduce partials + bias + L2 normalize ----------------
// one thread per (b, n): grid 64, block 256
__global__ __launch_bounds__(256) void reduce_norm_kernel(
    const float* __restrict__ partials, const float* __restrict__ lin_b,
    float* __restrict__ cpl)
{
    int idx = blockIdx.x * 256 + threadIdx.x;   // b*256 + n
    int b = idx >> 8, n = idx & 255;
    float c[32];
    const float* lb = lin_b + n * 32;
    #pragma unroll
    for (int k = 0; k < 32; ++k) c[k] = lb[k];
    const float* pp = partials + (size_t)b * GN + n * 32;
    #pragma unroll
    for (int y = 0; y < KSPLIT; ++y) {
        const float4* p4 = (const float4*)(pp + (size_t)y * (64 * GN));
        #pragma unroll
        for (int k4 = 0; k4 < 8; ++k4) {
            float4 v = p4[k4];
            c[k4 * 4 + 0] += v.x; c[k4 * 4 + 1] += v.y;
            c[k4 * 4 + 2] += v.z; c[k4 * 4 + 3] += v.w;
        }
    }
    float ss = 0.f;
    #pragma unroll
    for (int k = 0; k < 32; ++k) ss += c[k] * c[k];
    float inv = 1.0f / sqrtf(ss);
    float4* o4 = (float4*)(cpl + (size_t)idx * 32);
    #pragma unroll
    for (int k4 = 0; k4 < 8; ++k4) {
        float4 v;
        v.x = c[k4 * 4 + 0] * inv; v.y = c[k4 * 4 + 1] * inv;
        v.z = c[k4 * 4 + 2] * inv; v.w = c[k4 * 4 + 3] * inv;
        o4[k4] = v;
    }
}

// ---------------- Kernel 4: scatter rows of K + nonzero counts ----------------
// one wave per (b,n) row; grid 4096, block 256
__global__ __launch_bounds__(256) void scatter_kernel(
    const float* __restrict__ cpl, const int* __restrict__ conn,
    float* __restrict__ Kout, float* __restrict__ ncount)
{
    __shared__ float rows[4][256];
    int lane = threadIdx.x & 63, wid = threadIdx.x >> 6;
    int ridx = blockIdx.x * 4 + wid;   // b*256 + n
    int n = ridx & 255;

    #pragma unroll
    for (int i = 0; i < 4; ++i) rows[wid][lane * 4 + i] = 0.f;
    __syncthreads();
    if (lane < 32) {
        int j = conn[n * 32 + lane];
        float v = cpl[(size_t)ridx * 32 + lane];
        atomicAdd(&rows[wid][j], v);
    }
    __syncthreads();
    float4 vv = *(float4*)&rows[wid][lane * 4];
    int cnt = (vv.x != 0.f) + (vv.y != 0.f) + (vv.z != 0.f) + (vv.w != 0.f);
    #pragma unroll
    for (int off = 32; off; off >>= 1) cnt += __shfl_down(cnt, off);
    *(float4*)&Kout[(size_t)ridx * 256 + lane * 4] = vv;
    if (lane == 0) ncount[ridx] = (float)cnt;
}

// ---------------- Kernel 5: Kuramoto Euler integration ----------------
// one block per batch; thread n owns oscillator n
__global__ __launch_bounds__(256) void ode_kernel(
    const float* __restrict__ cpl, const int* __restrict__ conn,
    const float* __restrict__ ncount, const float* __restrict__ phase0,
    float* __restrict__ phases)
{
    __shared__ float ssh[256], csh[256];
    int b = blockIdx.x, n = threadIdx.x;
    float w[32]; int j[32];
    #pragma unroll
    for (int k = 0; k < 32; ++k) {
        w[k] = cpl[(size_t)(b * 256 + n) * 32 + k];
        j[k] = conn[n * 32 + k];
    }
    float inv = 1.0f / ncount[b * 256 + n];
    float ph = phase0[b * 256 + n];
    float* out = phases + b * 256 + n;
    for (int t = 0; t < T_STEPS; ++t) {
        float s, c;
        sincosf(ph, &s, &c);
        ssh[n] = s; csh[n] = c;
        __syncthreads();
        float aS = 0.f, aC = 0.f;
        #pragma unroll
        for (int k = 0; k < 32; ++k) {
            aS = fmaf(w[k], ssh[j[k]], aS);
            aC = fmaf(w[k], csh[j[k]], aC);
        }
        ph += DT * (aS * c - aC * s) * inv;
        out[t * (BATCH * N_OSC)] = ph;
        __syncthreads();
    }
}

extern "C" void kernel_launch(void* const* d_in, const int* in_sizes, int n_in,
                              void* d_out, int out_size, void* d_ws, size_t ws_size,
                              hipStream_t stream) {
    const float* x      = (const float*)d_in[0];
    const float* w0     = (const float*)d_in[1];
    const float* b0     = (const float*)d_in[2];
    const float* w1     = (const float*)d_in[3];
    const float* b1     = (const float*)d_in[4];
    const float* lin_w  = (const float*)d_in[5];
    const float* lin_b  = (const float*)d_in[6];
    const int*   conn   = (const int*)d_in[7];
    const float* phase0 = (const float*)d_in[8];

    float* out    = (float*)d_out;
    float* phases = out;                 // [40][64][256]
    float* Kout   = out + PH_ELEMS;      // [64][256][256] — also used as GEMM partials scratch

    char* ws = (char*)d_ws;
    ushort_t* featB  = (ushort_t*)ws;                         // 1 MB
    float*    cpl    = (float*)(ws + (1 << 20));              // 2 MB
    float*    ncount = (float*)(ws + (3 << 20));              // 64 KB

    conv_kernel<<<dim3(256), dim3(256), 0, stream>>>(x, w0, b0, w1, b1, featB);
    gemm_kernel<<<dim3(GN / BN, KSPLIT), dim3(256), 0, stream>>>(featB, lin_w, Kout);
    reduce_norm_kernel<<<dim3(64), dim3(256), 0, stream>>>(Kout, lin_b, cpl);
    scatter_kernel<<<dim3(4096), dim3(256), 0, stream>>>(cpl, conn, Kout, ncount);
    ode_kernel<<<dim3(64), dim3(256), 0, stream>>>(cpl, conn, ncount, phase0, phases);
}

// Round 4
// 148.178 us; speedup vs baseline: 1.0083x; 1.0083x over previous
//
#include <hip/hip_runtime.h>

typedef __attribute__((ext_vector_type(8))) short short8;
typedef __attribute__((ext_vector_type(4))) float f32x4;
typedef unsigned short ushort_t;

#define N_OSC   256
#define NUM_CN  32
#define BATCH   64
#define T_STEPS 40
#define DT      0.125f

#define GK      8192
#define GN      8192
#define BN      64
#define KSPLIT  8
#define KRANGE  1024          // GK / KSPLIT
#define NCHUNK  32            // KRANGE / 32
#define PH_ELEMS 655360       // 40*64*256

__device__ __forceinline__ unsigned short f2bf(float f) {
    unsigned u = __float_as_uint(f);
    return (unsigned short)((u + 0x7fffu + ((u >> 16) & 1u)) >> 16);
}

__device__ __forceinline__ void stage16(const float* g, float* l) {
    __builtin_amdgcn_global_load_lds(
        (const __attribute__((address_space(1))) void*)g,
        (__attribute__((address_space(3))) void*)l, 16, 0, 0);
}

// ---------------- Kernel 1: conv stack -> feat (bf16) [round-0, passed] -----
__global__ __launch_bounds__(256) void conv_kernel(
    const float* __restrict__ x,  const float* __restrict__ w0,
    const float* __restrict__ b0, const float* __restrict__ w1,
    const float* __restrict__ b1, ushort_t* __restrict__ featB)
{
    __shared__ float xs[3][256];
    __shared__ float h0[16][256];
    int blk = blockIdx.x;
    int b = blk >> 2, og = blk & 3;
    int p = threadIdx.x;
    int y = p >> 4, x0 = p & 15;

    #pragma unroll
    for (int c = 0; c < 3; ++c) xs[c][p] = x[b * 768 + c * 256 + p];
    __syncthreads();

    float acc0[16];
    #pragma unroll
    for (int o = 0; o < 16; ++o) acc0[o] = b0[o];
    #pragma unroll
    for (int c = 0; c < 3; ++c)
        #pragma unroll
        for (int ky = 0; ky < 3; ++ky) {
            int yy = y + ky - 1;
            if (yy < 0 || yy > 15) continue;
            #pragma unroll
            for (int kx = 0; kx < 3; ++kx) {
                int xx = x0 + kx - 1;
                if (xx < 0 || xx > 15) continue;
                float v = xs[c][yy * 16 + xx];
                #pragma unroll
                for (int o = 0; o < 16; ++o)
                    acc0[o] = fmaf(v, w0[o * 27 + c * 9 + ky * 3 + kx], acc0[o]);
            }
        }
    #pragma unroll
    for (int o = 0; o < 16; ++o) h0[o][p] = tanhf(acc0[o]);
    __syncthreads();

    float acc1[8];
    #pragma unroll
    for (int o = 0; o < 8; ++o) acc1[o] = b1[og * 8 + o];
    for (int c = 0; c < 16; ++c)
        #pragma unroll
        for (int ky = 0; ky < 3; ++ky) {
            int yy = y + ky - 1;
            if (yy < 0 || yy > 15) continue;
            #pragma unroll
            for (int kx = 0; kx < 3; ++kx) {
                int xx = x0 + kx - 1;
                if (xx < 0 || xx > 15) continue;
                float v = h0[c][yy * 16 + xx];
                #pragma unroll
                for (int o = 0; o < 8; ++o)
                    acc1[o] = fmaf(v, w1[(og * 8 + o) * 144 + c * 9 + ky * 3 + kx], acc1[o]);
            }
        }
    #pragma unroll
    for (int o = 0; o < 8; ++o)
        featB[b * 8192 + (og * 8 + o) * 256 + p] = f2bf(tanhf(acc1[o]));
}

// ---------------- Kernel 2: BW-bound MFMA GEMM, LDS-staged B [new, on trial] -
__global__ __launch_bounds__(256, 4) void gemm_kernel(
    const ushort_t* __restrict__ featB,   // [64][8192] bf16
    const float*    __restrict__ lin_w,   // [8192][8192]
    float*          __restrict__ partials)// [KSPLIT][64][8192]
{
    __shared__ float ldsB[2][2048];       // [32][64] f32 per buffer
    int tid  = threadIdx.x;
    int lane = tid & 63, wid = tid >> 6;
    int l15  = lane & 15;
    int kg   = lane >> 4;                 // 0..3
    int n0   = blockIdx.x * BN;
    int k0   = blockIdx.y * KRANGE;

    // staging: thread tid, issue i covers LDS floats e..e+3, e = i*1024 + tid*4
    //   k = e>>6 ; c' = e&63 ; global col = c' ^ (((k>>3)&3)<<4)  (involution)
    int st_k0  = tid >> 4;                // k for issue 0 (0..15); issue1: +16
    int st_cp  = (tid & 15) * 4;          // c' base

    f32x4 acc[4];
    #pragma unroll
    for (int nf = 0; nf < 4; ++nf) acc[nf] = (f32x4){0.f, 0.f, 0.f, 0.f};

    const float* gb = lin_w + (size_t)k0 * GN + n0;

    // prologue: stage chunk 0 into buf 0
    {
        int k0a = st_k0,       c0a = st_cp ^ (((st_k0 >> 3) & 3) << 4);
        int k0b = st_k0 + 16,  c0b = st_cp ^ ((((st_k0 + 16) >> 3) & 3) << 4);
        stage16(gb + (size_t)k0a * GN + c0a, &ldsB[0][ (wid * 64) * 4 ]);
        stage16(gb + (size_t)k0b * GN + c0b, &ldsB[0][ 1024 + (wid * 64) * 4 ]);
    }

    int arow = wid * 16 + l15;
    const ushort_t* abase = featB + (size_t)arow * GK + k0 + kg * 8;

    #pragma unroll 2
    for (int c = 0; c < NCHUNK; ++c) {
        int cur = c & 1;
        __syncthreads();   // drains stage(c); protects buf[cur^1] reuse
        if (c + 1 < NCHUNK) {
            const float* gn = gb + (size_t)(c + 1) * 32 * GN;
            int k0a = st_k0,       c0a = st_cp ^ (((st_k0 >> 3) & 3) << 4);
            int k0b = st_k0 + 16,  c0b = st_cp ^ ((((st_k0 + 16) >> 3) & 3) << 4);
            stage16(gn + (size_t)k0a * GN + c0a, &ldsB[cur ^ 1][ (wid * 64) * 4 ]);
            stage16(gn + (size_t)k0b * GN + c0b, &ldsB[cur ^ 1][ 1024 + (wid * 64) * 4 ]);
        }
        short8 af = *(const short8*)(abase + c * 32);
        #pragma unroll
        for (int nf = 0; nf < 4; ++nf) {
            int colswz = (nf * 16 + l15) ^ (kg << 4);
            short8 bfrag;
            #pragma unroll
            for (int i = 0; i < 8; ++i)
                bfrag[i] = (short)f2bf(ldsB[cur][(kg * 8 + i) * 64 + colswz]);
            acc[nf] = __builtin_amdgcn_mfma_f32_16x16x32_bf16(af, bfrag, acc[nf], 0, 0, 0);
        }
    }

    // epilogue: each wave owns distinct rows -> direct coalesced store
    float* pout = partials + (size_t)blockIdx.y * (64 * GN) + n0;
    int r4 = (lane >> 4) * 4;
    #pragma unroll
    for (int nf = 0; nf < 4; ++nf)
        #pragma unroll
        for (int r = 0; r < 4; ++r)
            pout[(size_t)(wid * 16 + r4 + r) * GN + nf * 16 + l15] = acc[nf][r];
}

// ---------------- Kernel 3: reduce + bias + L2 normalize [round-0, passed] --
__global__ __launch_bounds__(256) void reduce_norm_kernel(
    const float* __restrict__ partials, const float* __restrict__ lin_b,
    float* __restrict__ cpl)
{
    int idx = blockIdx.x * 256 + threadIdx.x;   // b*256 + n
    int b = idx >> 8, n = idx & 255;
    float c[32];
    const float* lb = lin_b + n * 32;
    #pragma unroll
    for (int k = 0; k < 32; ++k) c[k] = lb[k];
    const float* pp = partials + (size_t)b * GN + n * 32;
    #pragma unroll
    for (int y = 0; y < KSPLIT; ++y) {
        const float4* p4 = (const float4*)(pp + (size_t)y * (64 * GN));
        #pragma unroll
        for (int k4 = 0; k4 < 8; ++k4) {
            float4 v = p4[k4];
            c[k4 * 4 + 0] += v.x; c[k4 * 4 + 1] += v.y;
            c[k4 * 4 + 2] += v.z; c[k4 * 4 + 3] += v.w;
        }
    }
    float ss = 0.f;
    #pragma unroll
    for (int k = 0; k < 32; ++k) ss += c[k] * c[k];
    float inv = 1.0f / sqrtf(ss);
    float4* o4 = (float4*)(cpl + (size_t)idx * 32);
    #pragma unroll
    for (int k4 = 0; k4 < 8; ++k4) {
        float4 v;
        v.x = c[k4 * 4 + 0] * inv; v.y = c[k4 * 4 + 1] * inv;
        v.z = c[k4 * 4 + 2] * inv; v.w = c[k4 * 4 + 3] * inv;
        o4[k4] = v;
    }
}

// ---------------- Kernel 4: scatter rows of K + counts [round-0, passed] ----
__global__ __launch_bounds__(256) void scatter_kernel(
    const float* __restrict__ cpl, const int* __restrict__ conn,
    float* __restrict__ Kout, float* __restrict__ ncount)
{
    __shared__ float rows[4][256];
    int lane = threadIdx.x & 63, wid = threadIdx.x >> 6;
    int ridx = blockIdx.x * 4 + wid;   // b*256 + n
    int n = ridx & 255;

    #pragma unroll
    for (int i = 0; i < 4; ++i) rows[wid][lane * 4 + i] = 0.f;
    __syncthreads();
    if (lane < 32) {
        int j = conn[n * 32 + lane];
        float v = cpl[(size_t)ridx * 32 + lane];
        atomicAdd(&rows[wid][j], v);
    }
    __syncthreads();
    float4 vv = *(float4*)&rows[wid][lane * 4];
    int cnt = (vv.x != 0.f) + (vv.y != 0.f) + (vv.z != 0.f) + (vv.w != 0.f);
    #pragma unroll
    for (int off = 32; off; off >>= 1) cnt += __shfl_down(cnt, off);
    *(float4*)&Kout[(size_t)ridx * 256 + lane * 4] = vv;
    if (lane == 0) ncount[ridx] = (float)cnt;
}

// ---------------- Kernel 5: Kuramoto Euler integration [round-0, passed] ----
__global__ __launch_bounds__(256) void ode_kernel(
    const float* __restrict__ cpl, const int* __restrict__ conn,
    const float* __restrict__ ncount, const float* __restrict__ phase0,
    float* __restrict__ phases)
{
    __shared__ float ssh[256], csh[256];
    int b = blockIdx.x, n = threadIdx.x;
    float w[32]; int j[32];
    #pragma unroll
    for (int k = 0; k < 32; ++k) {
        w[k] = cpl[(size_t)(b * 256 + n) * 32 + k];
        j[k] = conn[n * 32 + k];
    }
    float inv = 1.0f / ncount[b * 256 + n];
    float ph = phase0[b * 256 + n];
    float* out = phases + b * 256 + n;
    for (int t = 0; t < T_STEPS; ++t) {
        float s, c;
        sincosf(ph, &s, &c);
        ssh[n] = s; csh[n] = c;
        __syncthreads();
        float aS = 0.f, aC = 0.f;
        #pragma unroll
        for (int k = 0; k < 32; ++k) {
            aS = fmaf(w[k], ssh[j[k]], aS);
            aC = fmaf(w[k], csh[j[k]], aC);
        }
        ph += DT * (aS * c - aC * s) * inv;
        out[t * (BATCH * N_OSC)] = ph;
        __syncthreads();
    }
}

extern "C" void kernel_launch(void* const* d_in, const int* in_sizes, int n_in,
                              void* d_out, int out_size, void* d_ws, size_t ws_size,
                              hipStream_t stream) {
    const float* x      = (const float*)d_in[0];
    const float* w0     = (const float*)d_in[1];
    const float* b0     = (const float*)d_in[2];
    const float* w1     = (const float*)d_in[3];
    const float* b1     = (const float*)d_in[4];
    const float* lin_w  = (const float*)d_in[5];
    const float* lin_b  = (const float*)d_in[6];
    const int*   conn   = (const int*)d_in[7];
    const float* phase0 = (const float*)d_in[8];

    float* out    = (float*)d_out;
    float* phases = out;                 // [40][64][256]
    float* Kout   = out + PH_ELEMS;      // [64][256][256]

    char* ws = (char*)d_ws;
    ushort_t* featB    = (ushort_t*)ws;                // 1 MB @ 0
    float*    cpl      = (float*)(ws + (1 << 20));     // 2 MB @ 1M
    float*    ncount   = (float*)(ws + (3 << 20));     // 64 KB @ 3M
    float*    partials = (float*)(ws + (4 << 20));     // 16 MB @ 4M

    conv_kernel<<<dim3(256), dim3(256), 0, stream>>>(x, w0, b0, w1, b1, featB);
    gemm_kernel<<<dim3(GN / BN, KSPLIT), dim3(256), 0, stream>>>(featB, lin_w, partials);
    reduce_norm_kernel<<<dim3(64), dim3(256), 0, stream>>>(partials, lin_b, cpl);
    scatter_kernel<<<dim3(4096), dim3(256), 0, stream>>>(cpl, conn, Kout, ncount);
    ode_kernel<<<dim3(64), dim3(256), 0, stream>>>(cpl, conn, ncount, phase0, phases);
}

// Round 5
// 142.252 us; speedup vs baseline: 1.0503x; 1.0417x over previous
//
#include <hip/hip_runtime.h>

typedef __attribute__((ext_vector_type(8))) short short8;
typedef __attribute__((ext_vector_type(4))) float f32x4;
typedef unsigned short ushort_t;

#define N_OSC   256
#define NUM_CN  32
#define BATCH   64
#define T_STEPS 40
#define DT      0.125f

#define GK      8192
#define GN      8192
#define BN      64
#define KSPLIT  8
#define KRANGE  1024          // GK / KSPLIT
#define BK      64            // k-rows per chunk
#define NCHUNK  16            // KRANGE / BK
#define PH_ELEMS 655360       // 40*64*256

__device__ __forceinline__ unsigned short f2bf(float f) {
    unsigned u = __float_as_uint(f);
    return (unsigned short)((u + 0x7fffu + ((u >> 16) & 1u)) >> 16);
}

__device__ __forceinline__ void stage16(const float* g, float* l) {
    __builtin_amdgcn_global_load_lds(
        (const __attribute__((address_space(1))) void*)g,
        (__attribute__((address_space(3))) void*)l, 16, 0, 0);
}

// ---------------- Kernel 1: conv stack -> feat (bf16) [passed r1/r4] --------
__global__ __launch_bounds__(256) void conv_kernel(
    const float* __restrict__ x,  const float* __restrict__ w0,
    const float* __restrict__ b0, const float* __restrict__ w1,
    const float* __restrict__ b1, ushort_t* __restrict__ featB)
{
    __shared__ float xs[3][256];
    __shared__ float h0[16][256];
    int blk = blockIdx.x;
    int b = blk >> 2, og = blk & 3;
    int p = threadIdx.x;
    int y = p >> 4, x0 = p & 15;

    #pragma unroll
    for (int c = 0; c < 3; ++c) xs[c][p] = x[b * 768 + c * 256 + p];
    __syncthreads();

    float acc0[16];
    #pragma unroll
    for (int o = 0; o < 16; ++o) acc0[o] = b0[o];
    #pragma unroll
    for (int c = 0; c < 3; ++c)
        #pragma unroll
        for (int ky = 0; ky < 3; ++ky) {
            int yy = y + ky - 1;
            if (yy < 0 || yy > 15) continue;
            #pragma unroll
            for (int kx = 0; kx < 3; ++kx) {
                int xx = x0 + kx - 1;
                if (xx < 0 || xx > 15) continue;
                float v = xs[c][yy * 16 + xx];
                #pragma unroll
                for (int o = 0; o < 16; ++o)
                    acc0[o] = fmaf(v, w0[o * 27 + c * 9 + ky * 3 + kx], acc0[o]);
            }
        }
    #pragma unroll
    for (int o = 0; o < 16; ++o) h0[o][p] = tanhf(acc0[o]);
    __syncthreads();

    float acc1[8];
    #pragma unroll
    for (int o = 0; o < 8; ++o) acc1[o] = b1[og * 8 + o];
    for (int c = 0; c < 16; ++c)
        #pragma unroll
        for (int ky = 0; ky < 3; ++ky) {
            int yy = y + ky - 1;
            if (yy < 0 || yy > 15) continue;
            #pragma unroll
            for (int kx = 0; kx < 3; ++kx) {
                int xx = x0 + kx - 1;
                if (xx < 0 || xx > 15) continue;
                float v = h0[c][yy * 16 + xx];
                #pragma unroll
                for (int o = 0; o < 8; ++o)
                    acc1[o] = fmaf(v, w1[(og * 8 + o) * 144 + c * 9 + ky * 3 + kx], acc1[o]);
            }
        }
    #pragma unroll
    for (int o = 0; o < 8; ++o)
        featB[b * 8192 + (og * 8 + o) * 256 + p] = f2bf(tanhf(acc1[o]));
}

// ---------------- Kernel 2: BW-bound MFMA GEMM, BK=64 double-buffer ---------
// grid (128, 8), block 256. Wave w owns output rows w*16..w*16+15.
// B chunk [64 k][64 col] f32 (16 KB) staged via global_load_lds (4 issues/thr),
// XOR-16 col swizzle pre-applied on the global source (involution; read
// applies the same XOR; k>>3 ≡ kg (mod 4) on the read path).
__global__ __launch_bounds__(256, 4) void gemm_kernel(
    const ushort_t* __restrict__ featB,   // [64][8192] bf16
    const float*    __restrict__ lin_w,   // [8192][8192]
    float*          __restrict__ partials)// [KSPLIT][64][8192]
{
    __shared__ float ldsB[2][4096];       // [64][64] f32 per buffer
    int tid  = threadIdx.x;
    int lane = tid & 63, wid = tid >> 6;
    int l15  = lane & 15;
    int kg   = lane >> 4;                 // 0..3
    int n0   = blockIdx.x * BN;
    int k0   = blockIdx.y * KRANGE;

    // staging: issue i covers LDS floats e..e+3, e = i*1024 + tid*4
    //   k = i*16 + (tid>>4) ; c' = (tid&15)*4 ; src col = c' ^ (((k>>3)&3)<<4)
    int st_kb = tid >> 4;
    int st_cp = (tid & 15) * 4;

    f32x4 acc[4];
    #pragma unroll
    for (int nf = 0; nf < 4; ++nf) acc[nf] = (f32x4){0.f, 0.f, 0.f, 0.f};

    const float* gb = lin_w + (size_t)k0 * GN + n0;

    // prologue: stage chunk 0 into buf 0
    #pragma unroll
    for (int i = 0; i < 4; ++i) {
        int k = i * 16 + st_kb;
        int c0 = st_cp ^ (((k >> 3) & 3) << 4);
        stage16(gb + (size_t)k * GN + c0, &ldsB[0][ i * 1024 + wid * 256 ]);
    }

    int arow = wid * 16 + l15;
    const ushort_t* abase = featB + (size_t)arow * GK + k0 + kg * 8;

    #pragma unroll 2
    for (int c = 0; c < NCHUNK; ++c) {
        int cur = c & 1;
        __syncthreads();   // drains stage(c); protects buf[cur^1] reuse
        if (c + 1 < NCHUNK) {
            const float* gn = gb + (size_t)(c + 1) * BK * GN;
            #pragma unroll
            for (int i = 0; i < 4; ++i) {
                int k = i * 16 + st_kb;
                int c0 = st_cp ^ (((k >> 3) & 3) << 4);
                stage16(gn + (size_t)k * GN + c0, &ldsB[cur ^ 1][ i * 1024 + wid * 256 ]);
            }
        }
        #pragma unroll
        for (int kk = 0; kk < 2; ++kk) {
            short8 af = *(const short8*)(abase + c * BK + kk * 32);
            #pragma unroll
            for (int nf = 0; nf < 4; ++nf) {
                int colswz = (nf * 16 + l15) ^ (kg << 4);
                const float* bsrc = &ldsB[cur][(kk * 32 + kg * 8) * 64 + colswz];
                short8 bfrag;
                #pragma unroll
                for (int i = 0; i < 8; ++i)
                    bfrag[i] = (short)f2bf(bsrc[i * 64]);
                acc[nf] = __builtin_amdgcn_mfma_f32_16x16x32_bf16(af, bfrag, acc[nf], 0, 0, 0);
            }
        }
    }

    // epilogue: each wave owns distinct rows -> direct coalesced store
    float* pout = partials + (size_t)blockIdx.y * (64 * GN) + n0;
    int r4 = (lane >> 4) * 4;
    #pragma unroll
    for (int nf = 0; nf < 4; ++nf)
        #pragma unroll
        for (int r = 0; r < 4; ++r)
            pout[(size_t)(wid * 16 + r4 + r) * GN + nf * 16 + l15] = acc[nf][r];
}

// ---------------- Kernel 3: reduce + bias + L2 normalize [regrid 128x128] ---
__global__ __launch_bounds__(128) void reduce_norm_kernel(
    const float* __restrict__ partials, const float* __restrict__ lin_b,
    float* __restrict__ cpl)
{
    int idx = blockIdx.x * 128 + threadIdx.x;   // b*256 + n
    int b = idx >> 8, n = idx & 255;
    float c[32];
    const float* lb = lin_b + n * 32;
    #pragma unroll
    for (int k = 0; k < 32; ++k) c[k] = lb[k];
    const float* pp = partials + (size_t)b * GN + n * 32;
    #pragma unroll
    for (int y = 0; y < KSPLIT; ++y) {
        const float4* p4 = (const float4*)(pp + (size_t)y * (64 * GN));
        #pragma unroll
        for (int k4 = 0; k4 < 8; ++k4) {
            float4 v = p4[k4];
            c[k4 * 4 + 0] += v.x; c[k4 * 4 + 1] += v.y;
            c[k4 * 4 + 2] += v.z; c[k4 * 4 + 3] += v.w;
        }
    }
    float ss = 0.f;
    #pragma unroll
    for (int k = 0; k < 32; ++k) ss += c[k] * c[k];
    float inv = 1.0f / sqrtf(ss);
    float4* o4 = (float4*)(cpl + (size_t)idx * 32);
    #pragma unroll
    for (int k4 = 0; k4 < 8; ++k4) {
        float4 v;
        v.x = c[k4 * 4 + 0] * inv; v.y = c[k4 * 4 + 1] * inv;
        v.z = c[k4 * 4 + 2] * inv; v.w = c[k4 * 4 + 3] * inv;
        o4[k4] = v;
    }
}

// ---------------- Kernel 4: scatter rows of K + counts [passed r1/r4] -------
__global__ __launch_bounds__(256) void scatter_kernel(
    const float* __restrict__ cpl, const int* __restrict__ conn,
    float* __restrict__ Kout, float* __restrict__ ncount)
{
    __shared__ float rows[4][256];
    int lane = threadIdx.x & 63, wid = threadIdx.x >> 6;
    int ridx = blockIdx.x * 4 + wid;   // b*256 + n
    int n = ridx & 255;

    #pragma unroll
    for (int i = 0; i < 4; ++i) rows[wid][lane * 4 + i] = 0.f;
    __syncthreads();
    if (lane < 32) {
        int j = conn[n * 32 + lane];
        float v = cpl[(size_t)ridx * 32 + lane];
        atomicAdd(&rows[wid][j], v);
    }
    __syncthreads();
    float4 vv = *(float4*)&rows[wid][lane * 4];
    int cnt = (vv.x != 0.f) + (vv.y != 0.f) + (vv.z != 0.f) + (vv.w != 0.f);
    #pragma unroll
    for (int off = 32; off; off >>= 1) cnt += __shfl_down(cnt, off);
    *(float4*)&Kout[(size_t)ridx * 256 + lane * 4] = vv;
    if (lane == 0) ncount[ridx] = (float)cnt;
}

// ---------------- Kernel 5: Kuramoto Euler integration [passed r1/r4] -------
__global__ __launch_bounds__(256) void ode_kernel(
    const float* __restrict__ cpl, const int* __restrict__ conn,
    const float* __restrict__ ncount, const float* __restrict__ phase0,
    float* __restrict__ phases)
{
    __shared__ float ssh[256], csh[256];
    int b = blockIdx.x, n = threadIdx.x;
    float w[32]; int j[32];
    #pragma unroll
    for (int k = 0; k < 32; ++k) {
        w[k] = cpl[(size_t)(b * 256 + n) * 32 + k];
        j[k] = conn[n * 32 + k];
    }
    float inv = 1.0f / ncount[b * 256 + n];
    float ph = phase0[b * 256 + n];
    float* out = phases + b * 256 + n;
    for (int t = 0; t < T_STEPS; ++t) {
        float s, c;
        sincosf(ph, &s, &c);
        ssh[n] = s; csh[n] = c;
        __syncthreads();
        float aS = 0.f, aC = 0.f;
        #pragma unroll
        for (int k = 0; k < 32; ++k) {
            aS = fmaf(w[k], ssh[j[k]], aS);
            aC = fmaf(w[k], csh[j[k]], aC);
        }
        ph += DT * (aS * c - aC * s) * inv;
        out[t * (BATCH * N_OSC)] = ph;
        __syncthreads();
    }
}

extern "C" void kernel_launch(void* const* d_in, const int* in_sizes, int n_in,
                              void* d_out, int out_size, void* d_ws, size_t ws_size,
                              hipStream_t stream) {
    const float* x      = (const float*)d_in[0];
    const float* w0     = (const float*)d_in[1];
    const float* b0     = (const float*)d_in[2];
    const float* w1     = (const float*)d_in[3];
    const float* b1     = (const float*)d_in[4];
    const float* lin_w  = (const float*)d_in[5];
    const float* lin_b  = (const float*)d_in[6];
    const int*   conn   = (const int*)d_in[7];
    const float* phase0 = (const float*)d_in[8];

    float* out    = (float*)d_out;
    float* phases = out;                 // [40][64][256]
    float* Kout   = out + PH_ELEMS;      // [64][256][256]

    char* ws = (char*)d_ws;
    ushort_t* featB    = (ushort_t*)ws;                // 1 MB @ 0
    float*    cpl      = (float*)(ws + (1 << 20));     // 2 MB @ 1M
    float*    ncount   = (float*)(ws + (3 << 20));     // 64 KB @ 3M
    float*    partials = (float*)(ws + (4 << 20));     // 16 MB @ 4M

    conv_kernel<<<dim3(256), dim3(256), 0, stream>>>(x, w0, b0, w1, b1, featB);
    gemm_kernel<<<dim3(GN / BN, KSPLIT), dim3(256), 0, stream>>>(featB, lin_w, partials);
    reduce_norm_kernel<<<dim3(128), dim3(128), 0, stream>>>(partials, lin_b, cpl);
    scatter_kernel<<<dim3(4096), dim3(256), 0, stream>>>(cpl, conn, Kout, ncount);
    ode_kernel<<<dim3(64), dim3(256), 0, stream>>>(cpl, conn, ncount, phase0, phases);
}

// Round 6
// 125.104 us; speedup vs baseline: 1.1942x; 1.1371x over previous
//
#include <hip/hip_runtime.h>

typedef __attribute__((ext_vector_type(8))) short short8;
typedef __attribute__((ext_vector_type(4))) float f32x4;
typedef unsigned short ushort_t;

#define N_OSC   256
#define NUM_CN  32
#define BATCH   64
#define T_STEPS 40
#define DT      0.125f

#define GK      8192
#define GN      8192
#define BN      64
#define KSPLIT  8
#define KRANGE  1024          // GK / KSPLIT
#define BK      64            // k-rows per chunk
#define NCHUNK  16            // KRANGE / BK
#define PH_ELEMS 655360       // 40*64*256

__device__ __forceinline__ unsigned short f2bf(float f) {
    unsigned u = __float_as_uint(f);
    return (unsigned short)((u + 0x7fffu + ((u >> 16) & 1u)) >> 16);
}

__device__ __forceinline__ void stage16(const float* g, float* l) {
    __builtin_amdgcn_global_load_lds(
        (const __attribute__((address_space(1))) void*)g,
        (__attribute__((address_space(3))) void*)l, 16, 0, 0);
}

// ---------------- Kernel 1: conv stack -> feat (bf16) [passed r1/r4/r5] -----
__global__ __launch_bounds__(256) void conv_kernel(
    const float* __restrict__ x,  const float* __restrict__ w0,
    const float* __restrict__ b0, const float* __restrict__ w1,
    const float* __restrict__ b1, ushort_t* __restrict__ featB)
{
    __shared__ float xs[3][256];
    __shared__ float h0[16][256];
    int blk = blockIdx.x;
    int b = blk >> 2, og = blk & 3;
    int p = threadIdx.x;
    int y = p >> 4, x0 = p & 15;

    #pragma unroll
    for (int c = 0; c < 3; ++c) xs[c][p] = x[b * 768 + c * 256 + p];
    __syncthreads();

    float acc0[16];
    #pragma unroll
    for (int o = 0; o < 16; ++o) acc0[o] = b0[o];
    #pragma unroll
    for (int c = 0; c < 3; ++c)
        #pragma unroll
        for (int ky = 0; ky < 3; ++ky) {
            int yy = y + ky - 1;
            if (yy < 0 || yy > 15) continue;
            #pragma unroll
            for (int kx = 0; kx < 3; ++kx) {
                int xx = x0 + kx - 1;
                if (xx < 0 || xx > 15) continue;
                float v = xs[c][yy * 16 + xx];
                #pragma unroll
                for (int o = 0; o < 16; ++o)
                    acc0[o] = fmaf(v, w0[o * 27 + c * 9 + ky * 3 + kx], acc0[o]);
            }
        }
    #pragma unroll
    for (int o = 0; o < 16; ++o) h0[o][p] = tanhf(acc0[o]);
    __syncthreads();

    float acc1[8];
    #pragma unroll
    for (int o = 0; o < 8; ++o) acc1[o] = b1[og * 8 + o];
    for (int c = 0; c < 16; ++c)
        #pragma unroll
        for (int ky = 0; ky < 3; ++ky) {
            int yy = y + ky - 1;
            if (yy < 0 || yy > 15) continue;
            #pragma unroll
            for (int kx = 0; kx < 3; ++kx) {
                int xx = x0 + kx - 1;
                if (xx < 0 || xx > 15) continue;
                float v = h0[c][yy * 16 + xx];
                #pragma unroll
                for (int o = 0; o < 8; ++o)
                    acc1[o] = fmaf(v, w1[(og * 8 + o) * 144 + c * 9 + ky * 3 + kx], acc1[o]);
            }
        }
    #pragma unroll
    for (int o = 0; o < 8; ++o)
        featB[b * 8192 + (og * 8 + o) * 256 + p] = f2bf(tanhf(acc1[o]));
}

// ---------------- Kernel 2: BW-bound MFMA GEMM, BK=64 dbuf [passed r5] ------
__global__ __launch_bounds__(256, 4) void gemm_kernel(
    const ushort_t* __restrict__ featB,   // [64][8192] bf16
    const float*    __restrict__ lin_w,   // [8192][8192]
    float*          __restrict__ partials)// [KSPLIT][64][8192]
{
    __shared__ float ldsB[2][4096];       // [64][64] f32 per buffer
    int tid  = threadIdx.x;
    int lane = tid & 63, wid = tid >> 6;
    int l15  = lane & 15;
    int kg   = lane >> 4;                 // 0..3
    int n0   = blockIdx.x * BN;
    int k0   = blockIdx.y * KRANGE;

    // staging: issue i covers LDS floats e..e+3, e = i*1024 + tid*4
    //   k = i*16 + (tid>>4) ; c' = (tid&15)*4 ; src col = c' ^ (((k>>3)&3)<<4)
    int st_kb = tid >> 4;
    int st_cp = (tid & 15) * 4;

    f32x4 acc[4];
    #pragma unroll
    for (int nf = 0; nf < 4; ++nf) acc[nf] = (f32x4){0.f, 0.f, 0.f, 0.f};

    const float* gb = lin_w + (size_t)k0 * GN + n0;

    // prologue: stage chunk 0 into buf 0
    #pragma unroll
    for (int i = 0; i < 4; ++i) {
        int k = i * 16 + st_kb;
        int c0 = st_cp ^ (((k >> 3) & 3) << 4);
        stage16(gb + (size_t)k * GN + c0, &ldsB[0][ i * 1024 + wid * 256 ]);
    }

    int arow = wid * 16 + l15;
    const ushort_t* abase = featB + (size_t)arow * GK + k0 + kg * 8;

    #pragma unroll 2
    for (int c = 0; c < NCHUNK; ++c) {
        int cur = c & 1;
        __syncthreads();   // drains stage(c); protects buf[cur^1] reuse
        if (c + 1 < NCHUNK) {
            const float* gn = gb + (size_t)(c + 1) * BK * GN;
            #pragma unroll
            for (int i = 0; i < 4; ++i) {
                int k = i * 16 + st_kb;
                int c0 = st_cp ^ (((k >> 3) & 3) << 4);
                stage16(gn + (size_t)k * GN + c0, &ldsB[cur ^ 1][ i * 1024 + wid * 256 ]);
            }
        }
        #pragma unroll
        for (int kk = 0; kk < 2; ++kk) {
            short8 af = *(const short8*)(abase + c * BK + kk * 32);
            #pragma unroll
            for (int nf = 0; nf < 4; ++nf) {
                int colswz = (nf * 16 + l15) ^ (kg << 4);
                const float* bsrc = &ldsB[cur][(kk * 32 + kg * 8) * 64 + colswz];
                short8 bfrag;
                #pragma unroll
                for (int i = 0; i < 8; ++i)
                    bfrag[i] = (short)f2bf(bsrc[i * 64]);
                acc[nf] = __builtin_amdgcn_mfma_f32_16x16x32_bf16(af, bfrag, acc[nf], 0, 0, 0);
            }
        }
    }

    // epilogue: each wave owns distinct rows -> direct coalesced store
    float* pout = partials + (size_t)blockIdx.y * (64 * GN) + n0;
    int r4 = (lane >> 4) * 4;
    #pragma unroll
    for (int nf = 0; nf < 4; ++nf)
        #pragma unroll
        for (int r = 0; r < 4; ++r)
            pout[(size_t)(wid * 16 + r4 + r) * GN + nf * 16 + l15] = acc[nf][r];
}

// ---------------- Kernel 3: reduce + bias + L2 normalize [passed r5] --------
__global__ __launch_bounds__(128) void reduce_norm_kernel(
    const float* __restrict__ partials, const float* __restrict__ lin_b,
    float* __restrict__ cpl)
{
    int idx = blockIdx.x * 128 + threadIdx.x;   // b*256 + n
    int b = idx >> 8, n = idx & 255;
    float c[32];
    const float* lb = lin_b + n * 32;
    #pragma unroll
    for (int k = 0; k < 32; ++k) c[k] = lb[k];
    const float* pp = partials + (size_t)b * GN + n * 32;
    #pragma unroll
    for (int y = 0; y < KSPLIT; ++y) {
        const float4* p4 = (const float4*)(pp + (size_t)y * (64 * GN));
        #pragma unroll
        for (int k4 = 0; k4 < 8; ++k4) {
            float4 v = p4[k4];
            c[k4 * 4 + 0] += v.x; c[k4 * 4 + 1] += v.y;
            c[k4 * 4 + 2] += v.z; c[k4 * 4 + 3] += v.w;
        }
    }
    float ss = 0.f;
    #pragma unroll
    for (int k = 0; k < 32; ++k) ss += c[k] * c[k];
    float inv = 1.0f / sqrtf(ss);
    float4* o4 = (float4*)(cpl + (size_t)idx * 32);
    #pragma unroll
    for (int k4 = 0; k4 < 8; ++k4) {
        float4 v;
        v.x = c[k4 * 4 + 0] * inv; v.y = c[k4 * 4 + 1] * inv;
        v.z = c[k4 * 4 + 2] * inv; v.w = c[k4 * 4 + 3] * inv;
        o4[k4] = v;
    }
}

// ---------------- Kernel 4: scatter rows of K + counts [passed r1/r4/r5] ----
__global__ __launch_bounds__(256) void scatter_kernel(
    const float* __restrict__ cpl, const int* __restrict__ conn,
    float* __restrict__ Kout, float* __restrict__ ncount)
{
    __shared__ float rows[4][256];
    int lane = threadIdx.x & 63, wid = threadIdx.x >> 6;
    int ridx = blockIdx.x * 4 + wid;   // b*256 + n
    int n = ridx & 255;

    #pragma unroll
    for (int i = 0; i < 4; ++i) rows[wid][lane * 4 + i] = 0.f;
    __syncthreads();
    if (lane < 32) {
        int j = conn[n * 32 + lane];
        float v = cpl[(size_t)ridx * 32 + lane];
        atomicAdd(&rows[wid][j], v);
    }
    __syncthreads();
    float4 vv = *(float4*)&rows[wid][lane * 4];
    int cnt = (vv.x != 0.f) + (vv.y != 0.f) + (vv.z != 0.f) + (vv.w != 0.f);
    #pragma unroll
    for (int off = 32; off; off >>= 1) cnt += __shfl_down(cnt, off);
    *(float4*)&Kout[(size_t)ridx * 256 + lane * 4] = vv;
    if (lane == 0) ncount[ridx] = (float)cnt;
}

// ---------------- Kernel 5: Kuramoto Euler integration ----------------------
// Same structure/barriers as the r1/r4/r5-proven version; two local changes:
// (a) sin/cos packed as float2 in LDS -> 32x ds_read_b64 gathers (was 64x b32)
// (b) __sincosf fast trig (|ph| <~ 7; err ~1e-5/step, well inside threshold)
__global__ __launch_bounds__(256) void ode_kernel(
    const float* __restrict__ cpl, const int* __restrict__ conn,
    const float* __restrict__ ncount, const float* __restrict__ phase0,
    float* __restrict__ phases)
{
    __shared__ float2 sc[256];
    int b = blockIdx.x, n = threadIdx.x;
    float w[32]; int j[32];
    #pragma unroll
    for (int k = 0; k < 32; ++k) {
        w[k] = cpl[(size_t)(b * 256 + n) * 32 + k];
        j[k] = conn[n * 32 + k];
    }
    float inv = 1.0f / ncount[b * 256 + n];
    float ph = phase0[b * 256 + n];
    float* out = phases + b * 256 + n;
    for (int t = 0; t < T_STEPS; ++t) {
        float s, c;
        __sincosf(ph, &s, &c);
        sc[n] = make_float2(s, c);
        __syncthreads();
        float aS = 0.f, aC = 0.f;
        #pragma unroll
        for (int k = 0; k < 32; ++k) {
            float2 v = sc[j[k]];
            aS = fmaf(w[k], v.x, aS);
            aC = fmaf(w[k], v.y, aC);
        }
        ph += DT * (aS * c - aC * s) * inv;
        out[t * (BATCH * N_OSC)] = ph;
        __syncthreads();
    }
}

extern "C" void kernel_launch(void* const* d_in, const int* in_sizes, int n_in,
                              void* d_out, int out_size, void* d_ws, size_t ws_size,
                              hipStream_t stream) {
    const float* x      = (const float*)d_in[0];
    const float* w0     = (const float*)d_in[1];
    const float* b0     = (const float*)d_in[2];
    const float* w1     = (const float*)d_in[3];
    const float* b1     = (const float*)d_in[4];
    const float* lin_w  = (const float*)d_in[5];
    const float* lin_b  = (const float*)d_in[6];
    const int*   conn   = (const int*)d_in[7];
    const float* phase0 = (const float*)d_in[8];

    float* out    = (float*)d_out;
    float* phases = out;                 // [40][64][256]
    float* Kout   = out + PH_ELEMS;      // [64][256][256]

    char* ws = (char*)d_ws;
    ushort_t* featB    = (ushort_t*)ws;                // 1 MB @ 0
    float*    cpl      = (float*)(ws + (1 << 20));     // 2 MB @ 1M
    float*    ncount   = (float*)(ws + (3 << 20));     // 64 KB @ 3M
    float*    partials = (float*)(ws + (4 << 20));     // 16 MB @ 4M

    conv_kernel<<<dim3(256), dim3(256), 0, stream>>>(x, w0, b0, w1, b1, featB);
    gemm_kernel<<<dim3(GN / BN, KSPLIT), dim3(256), 0, stream>>>(featB, lin_w, partials);
    reduce_norm_kernel<<<dim3(128), dim3(128), 0, stream>>>(partials, lin_b, cpl);
    scatter_kernel<<<dim3(4096), dim3(256), 0, stream>>>(cpl, conn, Kout, ncount);
    ode_kernel<<<dim3(64), dim3(256), 0, stream>>>(cpl, conn, ncount, phase0, phases);
}